// Round 5
// baseline (229.875 us; speedup 1.0000x reference)
//
#include <hip/hip_runtime.h>
#include <cstdint>
#include <cstddef>

#define D_MODEL 1024
#define N_HEADS 16
#define HEAD_DIM 64
#define SEQ 2048
#define BATCH 2

typedef __attribute__((ext_vector_type(8))) short bf16x8;
typedef __attribute__((ext_vector_type(4))) float f32x4;

// Hardware bf16 convert (RNE): 1 VALU op per 2 elements.
__device__ __forceinline__ unsigned cvtpk_bf16(float lo, float hi) {
    unsigned r;
    asm("v_cvt_pk_bf16_f32 %0, %1, %2" : "=v"(r) : "v"(lo), "v"(hi));
    return r;
}
__device__ __forceinline__ unsigned short f2bf_hw(float f) {
    return (unsigned short)cvtpk_bf16(f, 0.f);
}

// async global->LDS, 16 B per lane; LDS dst must be wave-base + lane*16.
__device__ __forceinline__ void gload_lds16(const unsigned short* g, unsigned short* l) {
    __builtin_amdgcn_global_load_lds(
        (const __attribute__((address_space(1))) unsigned int*)g,
        (__attribute__((address_space(3))) unsigned int*)l, 16, 0, 0);
}

// s_waitcnt immediates (gfx9: vmcnt[3:0]|[15:14], expcnt[6:4], lgkmcnt[11:8])
#define WAITCNT_VM4 0x0F74   // vmcnt(4)
#define WAITCNT_VM0 0x0F70   // vmcnt(0)

// ---------------------------------------------------------------------------
// Fused converts: x->bf16 | w_qkv->Wqt (permuted transpose, Q pre-scaled) |
// w_proj->Wpt.
// ---------------------------------------------------------------------------
__global__ __launch_bounds__(256) void fused_convert_kernel(
    const float* __restrict__ X, unsigned short* __restrict__ Xb,
    const float* __restrict__ Wq, unsigned short* __restrict__ Wqt,
    const float* __restrict__ Wp, unsigned short* __restrict__ Wpt)
{
    const int blk = blockIdx.x;
    const int tid = threadIdx.x;
    __shared__ float t[32][33];

    if (blk < 2048) {
        const int idx = blk * 256 + tid;
        const float4* src = (const float4*)X;
        float4 v0 = src[idx * 2], v1 = src[idx * 2 + 1];
        uint4 o;
        o.x = cvtpk_bf16(v0.x, v0.y);
        o.y = cvtpk_bf16(v0.z, v0.w);
        o.z = cvtpk_bf16(v1.x, v1.y);
        o.w = cvtpk_bf16(v1.z, v1.w);
        ((uint4*)Xb)[idx] = o;
    } else if (blk < 5120) {
        const int bb = blk - 2048;
        const int c0 = (bb % 96) * 32, r0 = (bb / 96) * 32;
        const int a = tid & 31, b = tid >> 5;
#pragma unroll
        for (int i = 0; i < 32; i += 8)
            t[b + i][a] = Wq[(size_t)(r0 + b + i) * (3 * D_MODEL) + c0 + a];
        __syncthreads();
#pragma unroll
        for (int i = 0; i < 32; i += 8) {
            const int c = c0 + b + i;
            const int which = c % 3;
            const int np = which * 1024 + c / 3;   // which*1024 + h*64 + d
            const float s = (which == 0) ? 0.125f : 1.0f;
            Wqt[(size_t)np * D_MODEL + r0 + a] = f2bf_hw(t[a][b + i] * s);
        }
    } else {
        const int bb = blk - 5120;
        const int c0 = (bb % 32) * 32, r0 = (bb / 32) * 32;
        const int a = tid & 31, b = tid >> 5;
#pragma unroll
        for (int i = 0; i < 32; i += 8)
            t[b + i][a] = Wp[(size_t)(r0 + b + i) * D_MODEL + c0 + a];
        __syncthreads();
#pragma unroll
        for (int i = 0; i < 32; i += 8)
            Wpt[(size_t)(c0 + b + i) * D_MODEL + r0 + a] = f2bf_hw(t[a][b + i]);
    }
}

// ---------------------------------------------------------------------------
// GEMM template v3: 256(M)x128(N) tile, BK=64, 8 waves (512 thr, 2Mx4N).
// LDS: A triple-buffered (3x32KB) + B double-buffered (2x16KB) = 128 KB ->
// 1 block/CU, 2 waves/SIMD.
// Schedule per K-tile t (ONE barrier per tile):
//   s_waitcnt vmcnt(4); s_barrier; sched_barrier(0);
//   stage B(t+1) -> B[(t+1)&1]   (2 gloads/thread)
//   stage A(t+2) -> A[(t+2)%3]   (4 gloads/thread)
//   ds_read frags + 32 MFMA (compiler-scheduled; setprio around MFMA)
// Race-freedom: stage targets differ from the slot being read this tile and
// from next tile's slot; the slot written was last read in tile t-1, whose
// ds_reads completed before the boundary barrier. Counted vmcnt: per-thread
// FIFO at boundary t = [A(t):4, B(t):2, A(t+1):4] -> wait 6 oldest = vmcnt(4);
// loads for tile t+1 stay in flight across the barrier (T4). Never drains
// mid-loop; final tile uses vmcnt(0).
// LDS is frag-order: A block fb=(f*2+kk): lane's 16B = A[f*16+(l&15)]
// [kk*32+(l>>4)*8], matching the MFMA A-frag read pattern exactly.
// ---------------------------------------------------------------------------
#define GEMM_A3B2_BODY(A_, B_, KBASE, NITER, BX_, BY_)                         \
    const int tid = threadIdx.x;                                               \
    const int w = tid >> 6, lane = tid & 63;                                   \
    const int l15 = lane & 15, quad = lane >> 4;                               \
    const int wr = w >> 2, wc = w & 3;                                         \
    const int row0 = (BY_) * 256, col0 = (BX_) * 128;                          \
    __shared__ unsigned short As[3 * 16384];                                   \
    __shared__ unsigned short Bs[2 * 8192];                                    \
    const f32x4 zero4 = {0.f, 0.f, 0.f, 0.f};                                  \
    f32x4 acc[8][2];                                                           \
    _Pragma("unroll") for (int i = 0; i < 8; i++)                              \
        _Pragma("unroll") for (int j = 0; j < 2; j++) acc[i][j] = zero4;       \
    auto stage_A = [&](int slot, int kt_) {                                    \
        _Pragma("unroll") for (int p = 0; p < 4; p++) {                        \
            const int fb = w * 4 + p, f = fb >> 1, kk = fb & 1;                \
            gload_lds16((A_) + (size_t)(row0 + f * 16 + l15) * D_MODEL         \
                            + (KBASE) + kt_ * 64 + kk * 32 + quad * 8,         \
                        &As[slot * 16384 + fb * 512 + lane * 8]);              \
        }                                                                      \
    };                                                                         \
    auto stage_B = [&](int slot, int kt_) {                                    \
        _Pragma("unroll") for (int p = 0; p < 2; p++) {                        \
            const int fb = w * 2 + p, g = fb >> 1, kk = fb & 1;                \
            gload_lds16((B_) + (size_t)(col0 + g * 16 + l15) * D_MODEL         \
                            + (KBASE) + kt_ * 64 + kk * 32 + quad * 8,         \
                        &Bs[slot * 8192 + fb * 512 + lane * 8]);               \
        }                                                                      \
    };                                                                         \
    stage_B(0, 0);                                                             \
    stage_A(0, 0);                                                             \
    stage_A(1 % 3, 1);                                                         \
    for (int t = 0; t < (NITER); t++) {                                        \
        if (t < (NITER) - 1) __builtin_amdgcn_s_waitcnt(WAITCNT_VM4);          \
        else                 __builtin_amdgcn_s_waitcnt(WAITCNT_VM0);          \
        __builtin_amdgcn_s_barrier();                                          \
        __builtin_amdgcn_sched_barrier(0);                                     \
        if (t + 1 < (NITER)) stage_B((t + 1) & 1, t + 1);                      \
        if (t + 2 < (NITER)) stage_A((t + 2) % 3, t + 2);                      \
        const int sa = (t % 3) * 16384, sbb = (t & 1) * 8192;                  \
        _Pragma("unroll") for (int kk = 0; kk < 2; kk++) {                     \
            bf16x8 af[8], bfr[2];                                              \
            _Pragma("unroll") for (int i = 0; i < 8; i++)                      \
                af[i] = *(const bf16x8*)&As[sa + ((wr * 8 + i) * 2 + kk) * 512 \
                                            + lane * 8];                       \
            _Pragma("unroll") for (int j = 0; j < 2; j++)                      \
                bfr[j] = *(const bf16x8*)&Bs[sbb + ((wc * 2 + j) * 2 + kk) * 512 \
                                             + lane * 8];                      \
            __builtin_amdgcn_s_setprio(1);                                     \
            _Pragma("unroll") for (int i = 0; i < 8; i++)                      \
                _Pragma("unroll") for (int j = 0; j < 2; j++)                  \
                    acc[i][j] = __builtin_amdgcn_mfma_f32_16x16x32_bf16(       \
                        af[i], bfr[j], acc[i][j], 0, 0, 0);                    \
            __builtin_amdgcn_s_setprio(0);                                     \
        }                                                                      \
    }

// GEMM1: Xb @ Wqt^T -> Q/K bf16 [bh][n][d]; V written directly transposed to
// Vt[bh][d][n]. Grid 24x16 = 384 blocks (1/CU, 1.5 dispatch rounds).
// XCD swizzle: 48/XCD as 12(bx) x 4(by) rect -> A 2MB + B 3MB = 5MB/XCD.
__global__ __launch_bounds__(512, 2) void gemm_qkv_mfma(
    const unsigned short* __restrict__ A, const unsigned short* __restrict__ B,
    unsigned short* __restrict__ Q, unsigned short* __restrict__ Kq,
    unsigned short* __restrict__ Vt)
{
    const int lin = blockIdx.x + 24 * blockIdx.y;   // 0..383, %8 = XCD
    const int xcd = lin & 7, tt = lin >> 3;         // tt: 0..47
    const int bx = (xcd & 1) * 12 + tt % 12;        // 0..23
    const int by = (xcd >> 1) * 4 + tt / 12;        // 0..15
    GEMM_A3B2_BODY(A, B, 0, 16, bx, by)
    // per-wave N window = 32 cols, never crosses a 64-col head boundary
    const int nbase = col0 + wc * 32;               // wave-uniform, mult of 32
    const int which = nbase >> 10;                  // 0:Q 1:K 2:V
    const int hh = (nbase >> 6) & 15;               // head
    const int dbase = nbase & 63;                   // 0 or 32
    if (which < 2) {
        unsigned short* const dst = (which == 0) ? Q : Kq;
#pragma unroll
        for (int i = 0; i < 8; i++) {
            const int rowb = row0 + wr * 128 + i * 16 + quad * 4;
            const int bb = rowb >> 11, n = rowb & (SEQ - 1);
#pragma unroll
            for (int rp = 0; rp < 2; rp++) {
#pragma unroll
                for (int j = 0; j < 2; j++) {
                    const unsigned u = cvtpk_bf16(acc[i][j][2 * rp], acc[i][j][2 * rp + 1]);
                    const int dd = dbase + j * 16 + l15;
                    unsigned short* p =
                        dst + (((size_t)(bb * N_HEADS + hh)) * SEQ + n + 2 * rp) * HEAD_DIM + dd;
                    p[0] = (unsigned short)u;
                    p[HEAD_DIM] = (unsigned short)(u >> 16);
                }
            }
        }
    } else {
#pragma unroll
        for (int i = 0; i < 8; i++) {
            const int rowb = row0 + wr * 128 + i * 16 + quad * 4;
            const int bb = rowb >> 11, n = rowb & (SEQ - 1);
#pragma unroll
            for (int rp = 0; rp < 2; rp++) {
#pragma unroll
                for (int j = 0; j < 2; j++) {
                    const unsigned u = cvtpk_bf16(acc[i][j][2 * rp], acc[i][j][2 * rp + 1]);
                    const int dd = dbase + j * 16 + l15;
                    *(unsigned*)&Vt[((size_t)(bb * N_HEADS + hh) * HEAD_DIM + dd) * SEQ
                                    + n + 2 * rp] = u;
                }
            }
        }
    }
}

// GEMM2: SPLIT-K=2, same template. Grid (8, 16, 2) = 256 blocks = exactly
// 1/CU single pass. K=512/block -> NITER=8.
__global__ __launch_bounds__(512, 2) void gemm_proj_splitk(
    const unsigned short* __restrict__ A, const unsigned short* __restrict__ B,
    float* __restrict__ P)
{
    const int lin = blockIdx.x + 8 * blockIdx.y;    // 0..127, %8 = XCD
    const int xcd = lin & 7, tt = lin >> 3;         // tt: 0..15
    const int bx = (xcd & 1) * 4 + tt % 4;          // 0..7
    const int by = (xcd >> 1) * 4 + tt / 4;         // 0..15
    const int kbase = blockIdx.z * 512;
    GEMM_A3B2_BODY(A, B, kbase, 8, bx, by)
    float* const dst = P + (size_t)blockIdx.z * (4096ull * 1024ull);
#pragma unroll
    for (int i = 0; i < 8; i++) {
#pragma unroll
        for (int r = 0; r < 4; r++) {
            const int row = row0 + wr * 128 + i * 16 + quad * 4 + r;
#pragma unroll
            for (int j = 0; j < 2; j++) {
                const int c = col0 + wc * 32 + j * 16 + l15;
                dst[(size_t)row * D_MODEL + c] = acc[i][j][r];
            }
        }
    }
}

// out = P0 + P1 (fp32). 4M floats = 1M float4; 1024 blocks x 256 thr x 4.
__global__ __launch_bounds__(256) void add_out_kernel(
    const float* __restrict__ P, float* __restrict__ out)
{
    const float4* p0 = (const float4*)P;
    const float4* p1 = (const float4*)(P + 4096ull * 1024ull);
    float4* o = (float4*)out;
    const int base = (blockIdx.x * 256 + threadIdx.x) * 4;
#pragma unroll
    for (int j = 0; j < 4; j++) {
        float4 a = p0[base + j], b = p1[base + j];
        float4 r = {a.x + b.x, a.y + b.y, a.z + b.z, a.w + b.w};
        o[base + j] = r;
    }
}

// ---------------------------------------------------------------------------
// Flash attention v5 (unchanged from R4): T13 defer-rescale, cvt_pk P-pack,
// per-lane l partial, setprio around MFMA. LDS 40 KB -> 4 blocks/CU.
// ---------------------------------------------------------------------------
__global__ __launch_bounds__(256) void flash_attn_kernel(
    const unsigned short* __restrict__ Q,
    const unsigned short* __restrict__ K,
    const unsigned short* __restrict__ Vt,
    unsigned short* __restrict__ O)
{
    const int idx = blockIdx.x;
    const int bh = idx & 31;
    const int qt2 = idx >> 5;
    const int hi = qt2 >> 3, lo = qt2 & 7;
    const int qt = (hi == 0) ? lo : (hi == 1) ? 31 - lo : (hi == 2) ? lo + 8 : 23 - lo;

    const int tid = threadIdx.x;
    const int w = tid >> 6, lane = tid & 63;
    const int l15 = lane & 15, quad = lane >> 4;

    __shared__ unsigned short Ks[2][4096];
    __shared__ unsigned short Vs[2][4096];
    __shared__ unsigned short Ps[4][1024];

    bf16x8 qf[2];
    {
        const unsigned short* qrow =
            Q + ((size_t)bh * SEQ + qt * 64 + w * 16 + l15) * HEAD_DIM;
        qf[0] = *(const bf16x8*)(qrow + quad * 8);
        qf[1] = *(const bf16x8*)(qrow + 32 + quad * 8);
    }

    const f32x4 zero4 = {0.f, 0.f, 0.f, 0.f};
    f32x4 o_acc[4] = {zero4, zero4, zero4, zero4};
    float m_i = -1e30f, l_i = 0.f;

    auto stage = [&](int bf, int kt_t) {
        const int key0 = kt_t * 64;
#pragma unroll
        for (int i = 0; i < 2; i++) {
            const int f = w * 2 + i;
            const int ct = f >> 1, kh = f & 1;
            gload_lds16(K + ((size_t)bh * SEQ + key0 + ct * 16 + l15) * HEAD_DIM
                          + kh * 32 + quad * 8,
                        &Ks[bf][f * 512 + lane * 8]);
            gload_lds16(Vt + ((size_t)bh * HEAD_DIM + ct * 16 + l15) * SEQ
                           + key0 + kh * 32 + quad * 8,
                        &Vs[bf][f * 512 + lane * 8]);
        }
    };

    stage(0, 0);
    int buf = 0;

    const int qg = qt * 64 + w * 16 + l15;

    for (int kt = 0; kt <= qt; kt++) {
        __syncthreads();
        if (kt < qt) stage(buf ^ 1, kt + 1);

        f32x4 st[4] = {zero4, zero4, zero4, zero4};
        __builtin_amdgcn_s_setprio(1);
#pragma unroll
        for (int kh = 0; kh < 2; kh++) {
#pragma unroll
            for (int ct = 0; ct < 4; ct++) {
                bf16x8 kf = *(const bf16x8*)&Ks[buf][(ct * 2 + kh) * 512 + lane * 8];
                st[ct] = __builtin_amdgcn_mfma_f32_16x16x32_bf16(kf, qf[kh], st[ct], 0, 0, 0);
            }
        }
        __builtin_amdgcn_s_setprio(0);

        float mt = -1e30f;
        if (kt == qt) {
#pragma unroll
            for (int ct = 0; ct < 4; ct++) {
#pragma unroll
                for (int r = 0; r < 4; r++) {
                    const int kg = kt * 64 + ct * 16 + quad * 4 + r;
                    float v = (kg > qg) ? -1e30f : st[ct][r];
                    st[ct][r] = v;
                    mt = fmaxf(mt, v);
                }
            }
        } else {
#pragma unroll
            for (int ct = 0; ct < 4; ct++)
#pragma unroll
                for (int r = 0; r < 4; r++)
                    mt = fmaxf(mt, st[ct][r]);
        }
        mt = fmaxf(mt, __shfl_xor(mt, 16));
        mt = fmaxf(mt, __shfl_xor(mt, 32));

        float mn = m_i;
        if (!__all(mt <= m_i + 8.0f)) {
            mn = fmaxf(m_i, mt);
            const float alpha = __expf(m_i - mn);
            m_i = mn;
            l_i *= alpha;
            float ar[4];
#pragma unroll
            for (int r = 0; r < 4; r++)
                ar[r] = __shfl(alpha, (lane & 48) | (quad * 4 + r));
#pragma unroll
            for (int dt = 0; dt < 4; dt++)
#pragma unroll
                for (int r = 0; r < 4; r++)
                    o_acc[dt][r] *= ar[r];
        }

        float ls = 0.f;
#pragma unroll
        for (int ct = 0; ct < 4; ct++) {
            const float p0 = __expf(st[ct][0] - mn);
            const float p1 = __expf(st[ct][1] - mn);
            const float p2 = __expf(st[ct][2] - mn);
            const float p3 = __expf(st[ct][3] - mn);
            ls += (p0 + p1) + (p2 + p3);
            uint2 pk2;
            pk2.x = cvtpk_bf16(p0, p1);
            pk2.y = cvtpk_bf16(p2, p3);
            const int addr = (ct >> 1) * 512 + ((ct & 1) * 2 + (quad >> 1)) * 128
                           + l15 * 8 + (quad & 1) * 4;
            *(uint2*)&Ps[w][addr] = pk2;
        }
        l_i += ls;

        __builtin_amdgcn_s_setprio(1);
#pragma unroll
        for (int kh = 0; kh < 2; kh++) {
            bf16x8 pa = *(const bf16x8*)&Ps[w][kh * 512 + quad * 128 + l15 * 8];
#pragma unroll
            for (int dt = 0; dt < 4; dt++) {
                bf16x8 vf = *(const bf16x8*)&Vs[buf][(dt * 2 + kh) * 512 + lane * 8];
                o_acc[dt] = __builtin_amdgcn_mfma_f32_16x16x32_bf16(pa, vf, o_acc[dt], 0, 0, 0);
            }
        }
        __builtin_amdgcn_s_setprio(0);
        buf ^= 1;
    }

    l_i += __shfl_xor(l_i, 16);
    l_i += __shfl_xor(l_i, 32);
    const float linv = 1.0f / l_i;
    float lr[4];
#pragma unroll
    for (int r = 0; r < 4; r++)
        lr[r] = __shfl(linv, (lane & 48) | (quad * 4 + r));

    const int b = bh >> 4, h = bh & 15;
#pragma unroll
    for (int r = 0; r < 4; r++) {
        const int q = qt * 64 + w * 16 + quad * 4 + r;
        unsigned short* orow = O + ((size_t)b * SEQ + q) * D_MODEL + h * HEAD_DIM;
#pragma unroll
        for (int dt = 0; dt < 4; dt++)
            orow[dt * 16 + l15] = f2bf_hw(o_acc[dt][r] * lr[r]);
    }
}

// ---------------------------------------------------------------------------
extern "C" void kernel_launch(void* const* d_in, const int* in_sizes, int n_in,
                              void* d_out, int out_size, void* d_ws, size_t ws_size,
                              hipStream_t stream) {
    const float* x      = (const float*)d_in[0];
    const float* w_qkv  = (const float*)d_in[1];
    const float* w_proj = (const float*)d_in[2];
    float* out = (float*)d_out;

    unsigned short* Xb  = (unsigned short*)d_ws;          // 4M shorts
    unsigned short* Wqt = Xb  + (size_t)4 * 1024 * 1024;  // 3M
    unsigned short* Wpt = Wqt + (size_t)3 * 1024 * 1024;  // 1M
    unsigned short* Qb  = Wpt + (size_t)1 * 1024 * 1024;  // 4M
    unsigned short* Kb  = Qb  + (size_t)4 * 1024 * 1024;  // 4M
    unsigned short* Vb  = Kb  + (size_t)4 * 1024 * 1024;  // 4M (spacer)
    unsigned short* Vtb = Vb  + (size_t)4 * 1024 * 1024;  // 4M (written by gemm)
    unsigned short* Ob  = Vtb + (size_t)4 * 1024 * 1024;  // 4M  (56 MB total)

    // Split-K partials alias Qb..Vtb (32 MB, dead after flash).
    float* Pp = (float*)Qb;

    fused_convert_kernel<<<dim3(6144), 256, 0, stream>>>(
        x, Xb, w_qkv, Wqt, w_proj, Wpt);

    gemm_qkv_mfma<<<dim3(24, 16), 512, 0, stream>>>(
        Xb, Wqt, Qb, Kb, Vtb);

    flash_attn_kernel<<<dim3(SEQ / 64 * BATCH * N_HEADS), 256, 0, stream>>>(
        Qb, Kb, Vtb, Ob);

    gemm_proj_splitk<<<dim3(8, 16, 2), 512, 0, stream>>>(
        Ob, Wpt, Pp);

    add_out_kernel<<<dim3(1024), 256, 0, stream>>>(Pp, out);
}

// Round 6
// 215.326 us; speedup vs baseline: 1.0676x; 1.0676x over previous
//
#include <hip/hip_runtime.h>
#include <cstdint>
#include <cstddef>

#define D_MODEL 1024
#define N_HEADS 16
#define HEAD_DIM 64
#define SEQ 2048
#define BATCH 2

typedef __attribute__((ext_vector_type(8))) short bf16x8;
typedef __attribute__((ext_vector_type(4))) float f32x4;

// Hardware bf16 convert (RNE): 1 VALU op per 2 elements.
__device__ __forceinline__ unsigned cvtpk_bf16(float lo, float hi) {
    unsigned r;
    asm("v_cvt_pk_bf16_f32 %0, %1, %2" : "=v"(r) : "v"(lo), "v"(hi));
    return r;
}
__device__ __forceinline__ unsigned short f2bf_hw(float f) {
    return (unsigned short)cvtpk_bf16(f, 0.f);
}

// async global->LDS, 16 B per lane; LDS dst must be wave-base + lane*16.
__device__ __forceinline__ void gload_lds16(const unsigned short* g, unsigned short* l) {
    __builtin_amdgcn_global_load_lds(
        (const __attribute__((address_space(1))) unsigned int*)g,
        (__attribute__((address_space(3))) unsigned int*)l, 16, 0, 0);
}

// s_waitcnt immediates (gfx9: vmcnt[3:0]|[15:14], expcnt[6:4], lgkmcnt[11:8])
#define WAITCNT_VM4 0x0F74   // vmcnt(4), expcnt/lgkmcnt = no-wait
#define WAITCNT_VM0 0x0F70   // vmcnt(0)

// ---------------------------------------------------------------------------
// Fused converts: x->bf16 | w_qkv->Wqt (permuted transpose, Q pre-scaled) |
// w_proj->Wpt.
// ---------------------------------------------------------------------------
__global__ __launch_bounds__(256) void fused_convert_kernel(
    const float* __restrict__ X, unsigned short* __restrict__ Xb,
    const float* __restrict__ Wq, unsigned short* __restrict__ Wqt,
    const float* __restrict__ Wp, unsigned short* __restrict__ Wpt)
{
    const int blk = blockIdx.x;
    const int tid = threadIdx.x;
    __shared__ float t[32][33];

    if (blk < 2048) {
        const int idx = blk * 256 + tid;
        const float4* src = (const float4*)X;
        float4 v0 = src[idx * 2], v1 = src[idx * 2 + 1];
        uint4 o;
        o.x = cvtpk_bf16(v0.x, v0.y);
        o.y = cvtpk_bf16(v0.z, v0.w);
        o.z = cvtpk_bf16(v1.x, v1.y);
        o.w = cvtpk_bf16(v1.z, v1.w);
        ((uint4*)Xb)[idx] = o;
    } else if (blk < 5120) {
        const int bb = blk - 2048;
        const int c0 = (bb % 96) * 32, r0 = (bb / 96) * 32;
        const int a = tid & 31, b = tid >> 5;
#pragma unroll
        for (int i = 0; i < 32; i += 8)
            t[b + i][a] = Wq[(size_t)(r0 + b + i) * (3 * D_MODEL) + c0 + a];
        __syncthreads();
#pragma unroll
        for (int i = 0; i < 32; i += 8) {
            const int c = c0 + b + i;
            const int which = c % 3;
            const int np = which * 1024 + c / 3;   // which*1024 + h*64 + d
            const float s = (which == 0) ? 0.125f : 1.0f;
            Wqt[(size_t)np * D_MODEL + r0 + a] = f2bf_hw(t[a][b + i] * s);
        }
    } else {
        const int bb = blk - 5120;
        const int c0 = (bb % 32) * 32, r0 = (bb / 32) * 32;
        const int a = tid & 31, b = tid >> 5;
#pragma unroll
        for (int i = 0; i < 32; i += 8)
            t[b + i][a] = Wp[(size_t)(r0 + b + i) * D_MODEL + c0 + a];
        __syncthreads();
#pragma unroll
        for (int i = 0; i < 32; i += 8)
            Wpt[(size_t)(c0 + b + i) * D_MODEL + r0 + a] = f2bf_hw(t[a][b + i]);
    }
}

// ---------------------------------------------------------------------------
// Pipelined GEMM core (R2-proven, verbatim): 128x128 tile, BK=32, triple-
// buffer LDS, stage depth 2, raw s_barrier + counted vmcnt(4) (never drains
// mid-loop). NO setprio (m190: negative in lockstep-barrier GEMM; R4 A/B
// confirmed -3us). LDS 48 KB -> 3 blocks/CU = 3 independent barrier groups.
// ---------------------------------------------------------------------------
#define GEMM_PIPE3_BODY(A_, B_, KBASE, NITER, BX_, BY_)                        \
    const int tid = threadIdx.x;                                               \
    const int w = tid >> 6, lane = tid & 63;                                   \
    const int l15 = lane & 15, quad = lane >> 4;                               \
    const int wr = w >> 1, wc = w & 1;                                         \
    const int row0 = (BY_) * 128, col0 = (BX_) * 128;                          \
    __shared__ unsigned short As[3][4096];                                     \
    __shared__ unsigned short Bs[3][4096];                                     \
    const f32x4 zero4 = {0.f, 0.f, 0.f, 0.f};                                  \
    f32x4 acc[4][4];                                                           \
    _Pragma("unroll") for (int i = 0; i < 4; i++)                              \
        _Pragma("unroll") for (int j = 0; j < 4; j++) acc[i][j] = zero4;       \
    auto stage_ = [&](int sb_, int kt_) {                                      \
        const int k0 = (KBASE) + kt_ * 32 + quad * 8;                          \
        _Pragma("unroll") for (int i = 0; i < 2; i++) {                        \
            const int f = w * 2 + i;                                           \
            gload_lds16((A_) + (size_t)(row0 + f * 16 + l15) * D_MODEL + k0,   \
                        &As[sb_][f * 512 + lane * 8]);                         \
            gload_lds16((B_) + (size_t)(col0 + f * 16 + l15) * D_MODEL + k0,   \
                        &Bs[sb_][f * 512 + lane * 8]);                         \
        }                                                                      \
    };                                                                         \
    stage_(0, 0);                                                              \
    stage_(1, 1);                                                              \
    int sb = 0;                                                                \
    for (int kt = 0; kt < (NITER); kt++) {                                     \
        if (kt < (NITER) - 1) {                                                \
            __builtin_amdgcn_s_waitcnt(WAITCNT_VM4);                           \
            __builtin_amdgcn_s_barrier();                                      \
            if (kt + 2 < (NITER)) stage_((sb + 2 > 2) ? sb - 1 : sb + 2, kt + 2); \
        } else {                                                               \
            __builtin_amdgcn_s_waitcnt(WAITCNT_VM0);                           \
            __builtin_amdgcn_s_barrier();                                      \
        }                                                                      \
        bf16x8 af[4], bfr[4];                                                  \
        _Pragma("unroll") for (int i = 0; i < 4; i++)                          \
            af[i] = *(const bf16x8*)&As[sb][(wr * 4 + i) * 512 + lane * 8];    \
        _Pragma("unroll") for (int j = 0; j < 4; j++)                          \
            bfr[j] = *(const bf16x8*)&Bs[sb][(wc * 4 + j) * 512 + lane * 8];   \
        _Pragma("unroll") for (int i = 0; i < 4; i++)                          \
            _Pragma("unroll") for (int j = 0; j < 4; j++)                      \
                acc[i][j] = __builtin_amdgcn_mfma_f32_16x16x32_bf16(           \
                    af[i], bfr[j], acc[i][j], 0, 0, 0);                        \
        sb = (sb == 2) ? 0 : sb + 1;                                           \
    }

// GEMM1: Xb @ Wqt^T -> Q/K bf16 [bh][n][d]; V written DIRECTLY TRANSPOSED
// to Vt[bh][d][n] (R4's win: kills the standalone v_transpose kernel;
// counters showed identical FETCH/WRITE -> scatter is L2-merged).
// T1 XCD swizzle: 96/XCD as 12(bx) x 8(by) rect -> ~5MB/XCD working set.
__global__ __launch_bounds__(256) void gemm_qkv_mfma(
    const unsigned short* __restrict__ A, const unsigned short* __restrict__ B,
    unsigned short* __restrict__ Q, unsigned short* __restrict__ Kq,
    unsigned short* __restrict__ Vt)
{
    const int lin = blockIdx.x + 24 * blockIdx.y;   // 0..767, %8 = XCD
    const int xcd = lin & 7, t = lin >> 3;          // t: 0..95
    const int bx = (xcd & 1) * 12 + t % 12;         // 0..23
    const int by = (xcd >> 1) * 8 + t / 12;         // 0..31
    GEMM_PIPE3_BODY(A, B, 0, 32, bx, by)
    const int nbase = col0 + wc * 64;              // wave-uniform, mult of 64
    const int which = nbase >> 10;                 // 0:Q 1:K 2:V
    if (which < 2) {
        unsigned short* const dst = (which == 0) ? Q : Kq;
#pragma unroll
        for (int i = 0; i < 4; i++) {
            const int rowb = row0 + wr * 64 + i * 16 + quad * 4;
            const int bb = rowb >> 11, n = rowb & (SEQ - 1);
#pragma unroll
            for (int rp = 0; rp < 2; rp++) {
#pragma unroll
                for (int j = 0; j < 4; j++) {
                    const unsigned u = cvtpk_bf16(acc[i][j][2 * rp], acc[i][j][2 * rp + 1]);
                    const int idx = (nbase + j * 16 + l15) & 1023;  // h*64+d
                    const int h = idx >> 6, dd = idx & 63;
                    unsigned short* p =
                        dst + (((size_t)(bb * N_HEADS + h)) * SEQ + n + 2 * rp) * HEAD_DIM + dd;
                    p[0] = (unsigned short)u;
                    p[HEAD_DIM] = (unsigned short)(u >> 16);
                }
            }
        }
    } else {
        // V: store transposed. Pair (row n+2rp, n+2rp+1) at fixed d -> one
        // dword at Vt[(bb*16+h)*64+d][n+2rp] (4B-aligned since n%4==0).
#pragma unroll
        for (int i = 0; i < 4; i++) {
            const int rowb = row0 + wr * 64 + i * 16 + quad * 4;
            const int bb = rowb >> 11, n = rowb & (SEQ - 1);
#pragma unroll
            for (int rp = 0; rp < 2; rp++) {
#pragma unroll
                for (int j = 0; j < 4; j++) {
                    const unsigned u = cvtpk_bf16(acc[i][j][2 * rp], acc[i][j][2 * rp + 1]);
                    const int idx = (nbase + j * 16 + l15) & 1023;  // h*64+d
                    *(unsigned*)&Vt[((size_t)(bb * N_HEADS + (idx >> 6)) * HEAD_DIM
                                     + (idx & 63)) * SEQ + n + 2 * rp] = u;
                }
            }
        }
    }
}

// GEMM2: SPLIT-K=2, pipelined. Grid (8, 32, 2). K=512/block, NITER=16.
// T1 XCD swizzle per z-slice: 32/XCD as 4(bx) x 8(by) rectangle.
__global__ __launch_bounds__(256) void gemm_proj_splitk(
    const unsigned short* __restrict__ A, const unsigned short* __restrict__ B,
    float* __restrict__ P)
{
    const int lin = blockIdx.x + 8 * blockIdx.y;    // 0..255, %8 = XCD
    const int xcd = lin & 7, t = lin >> 3;          // t: 0..31
    const int bx = (xcd & 1) * 4 + t % 4;           // 0..7
    const int by = (xcd >> 1) * 8 + t / 4;          // 0..31
    const int kbase = blockIdx.z * 512;
    GEMM_PIPE3_BODY(A, B, kbase, 16, bx, by)
    float* const dst = P + (size_t)blockIdx.z * (4096ull * 1024ull);
#pragma unroll
    for (int i = 0; i < 4; i++) {
#pragma unroll
        for (int r = 0; r < 4; r++) {
            const int row = row0 + wr * 64 + i * 16 + quad * 4 + r;
#pragma unroll
            for (int j = 0; j < 4; j++) {
                const int c = col0 + wc * 64 + j * 16 + l15;
                dst[(size_t)row * D_MODEL + c] = acc[i][j][r];
            }
        }
    }
}

// out = P0 + P1 (fp32). 4M floats = 1M float4; 1024 blocks x 256 thr x 4.
__global__ __launch_bounds__(256) void add_out_kernel(
    const float* __restrict__ P, float* __restrict__ out)
{
    const float4* p0 = (const float4*)P;
    const float4* p1 = (const float4*)(P + 4096ull * 1024ull);
    float4* o = (float4*)out;
    const int base = (blockIdx.x * 256 + threadIdx.x) * 4;
#pragma unroll
    for (int j = 0; j < 4; j++) {
        float4 a = p0[base + j], b = p1[base + j];
        float4 r = {a.x + b.x, a.y + b.y, a.z + b.z, a.w + b.w};
        o[base + j] = r;
    }
}

// ---------------------------------------------------------------------------
// Flash attention v5 (unchanged): T13 defer-rescale, cvt_pk P-pack, per-lane
// l partial, setprio around MFMA (kept: m191 attn regime, 4 independent
// blocks/CU). LDS 40 KB -> 4 blocks/CU, all 1024 blocks resident.
// ---------------------------------------------------------------------------
__global__ __launch_bounds__(256) void flash_attn_kernel(
    const unsigned short* __restrict__ Q,
    const unsigned short* __restrict__ K,
    const unsigned short* __restrict__ Vt,
    unsigned short* __restrict__ O)
{
    const int idx = blockIdx.x;
    const int bh = idx & 31;
    const int qt2 = idx >> 5;
    const int hi = qt2 >> 3, lo = qt2 & 7;
    const int qt = (hi == 0) ? lo : (hi == 1) ? 31 - lo : (hi == 2) ? lo + 8 : 23 - lo;

    const int tid = threadIdx.x;
    const int w = tid >> 6, lane = tid & 63;
    const int l15 = lane & 15, quad = lane >> 4;

    __shared__ unsigned short Ks[2][4096];
    __shared__ unsigned short Vs[2][4096];
    __shared__ unsigned short Ps[4][1024];

    bf16x8 qf[2];
    {
        const unsigned short* qrow =
            Q + ((size_t)bh * SEQ + qt * 64 + w * 16 + l15) * HEAD_DIM;
        qf[0] = *(const bf16x8*)(qrow + quad * 8);
        qf[1] = *(const bf16x8*)(qrow + 32 + quad * 8);
    }

    const f32x4 zero4 = {0.f, 0.f, 0.f, 0.f};
    f32x4 o_acc[4] = {zero4, zero4, zero4, zero4};
    float m_i = -1e30f, l_i = 0.f;

    auto stage = [&](int bf, int kt_t) {
        const int key0 = kt_t * 64;
#pragma unroll
        for (int i = 0; i < 2; i++) {
            const int f = w * 2 + i;
            const int ct = f >> 1, kh = f & 1;
            gload_lds16(K + ((size_t)bh * SEQ + key0 + ct * 16 + l15) * HEAD_DIM
                          + kh * 32 + quad * 8,
                        &Ks[bf][f * 512 + lane * 8]);
            gload_lds16(Vt + ((size_t)bh * HEAD_DIM + ct * 16 + l15) * SEQ
                           + key0 + kh * 32 + quad * 8,
                        &Vs[bf][f * 512 + lane * 8]);
        }
    };

    stage(0, 0);
    int buf = 0;

    const int qg = qt * 64 + w * 16 + l15;

    for (int kt = 0; kt <= qt; kt++) {
        __syncthreads();
        if (kt < qt) stage(buf ^ 1, kt + 1);

        f32x4 st[4] = {zero4, zero4, zero4, zero4};
        __builtin_amdgcn_s_setprio(1);
#pragma unroll
        for (int kh = 0; kh < 2; kh++) {
#pragma unroll
            for (int ct = 0; ct < 4; ct++) {
                bf16x8 kf = *(const bf16x8*)&Ks[buf][(ct * 2 + kh) * 512 + lane * 8];
                st[ct] = __builtin_amdgcn_mfma_f32_16x16x32_bf16(kf, qf[kh], st[ct], 0, 0, 0);
            }
        }
        __builtin_amdgcn_s_setprio(0);

        float mt = -1e30f;
        if (kt == qt) {
#pragma unroll
            for (int ct = 0; ct < 4; ct++) {
#pragma unroll
                for (int r = 0; r < 4; r++) {
                    const int kg = kt * 64 + ct * 16 + quad * 4 + r;
                    float v = (kg > qg) ? -1e30f : st[ct][r];
                    st[ct][r] = v;
                    mt = fmaxf(mt, v);
                }
            }
        } else {
#pragma unroll
            for (int ct = 0; ct < 4; ct++)
#pragma unroll
                for (int r = 0; r < 4; r++)
                    mt = fmaxf(mt, st[ct][r]);
        }
        mt = fmaxf(mt, __shfl_xor(mt, 16));
        mt = fmaxf(mt, __shfl_xor(mt, 32));

        float mn = m_i;
        if (!__all(mt <= m_i + 8.0f)) {
            mn = fmaxf(m_i, mt);
            const float alpha = __expf(m_i - mn);
            m_i = mn;
            l_i *= alpha;
            float ar[4];
#pragma unroll
            for (int r = 0; r < 4; r++)
                ar[r] = __shfl(alpha, (lane & 48) | (quad * 4 + r));
#pragma unroll
            for (int dt = 0; dt < 4; dt++)
#pragma unroll
                for (int r = 0; r < 4; r++)
                    o_acc[dt][r] *= ar[r];
        }

        float ls = 0.f;
#pragma unroll
        for (int ct = 0; ct < 4; ct++) {
            const float p0 = __expf(st[ct][0] - mn);
            const float p1 = __expf(st[ct][1] - mn);
            const float p2 = __expf(st[ct][2] - mn);
            const float p3 = __expf(st[ct][3] - mn);
            ls += (p0 + p1) + (p2 + p3);
            uint2 pk2;
            pk2.x = cvtpk_bf16(p0, p1);
            pk2.y = cvtpk_bf16(p2, p3);
            const int addr = (ct >> 1) * 512 + ((ct & 1) * 2 + (quad >> 1)) * 128
                           + l15 * 8 + (quad & 1) * 4;
            *(uint2*)&Ps[w][addr] = pk2;
        }
        l_i += ls;

        __builtin_amdgcn_s_setprio(1);
#pragma unroll
        for (int kh = 0; kh < 2; kh++) {
            bf16x8 pa = *(const bf16x8*)&Ps[w][kh * 512 + quad * 128 + l15 * 8];
#pragma unroll
            for (int dt = 0; dt < 4; dt++) {
                bf16x8 vf = *(const bf16x8*)&Vs[buf][(dt * 2 + kh) * 512 + lane * 8];
                o_acc[dt] = __builtin_amdgcn_mfma_f32_16x16x32_bf16(pa, vf, o_acc[dt], 0, 0, 0);
            }
        }
        __builtin_amdgcn_s_setprio(0);
        buf ^= 1;
    }

    l_i += __shfl_xor(l_i, 16);
    l_i += __shfl_xor(l_i, 32);
    const float linv = 1.0f / l_i;
    float lr[4];
#pragma unroll
    for (int r = 0; r < 4; r++)
        lr[r] = __shfl(linv, (lane & 48) | (quad * 4 + r));

    const int b = bh >> 4, h = bh & 15;
#pragma unroll
    for (int r = 0; r < 4; r++) {
        const int q = qt * 64 + w * 16 + quad * 4 + r;
        unsigned short* orow = O + ((size_t)b * SEQ + q) * D_MODEL + h * HEAD_DIM;
#pragma unroll
        for (int dt = 0; dt < 4; dt++)
            orow[dt * 16 + l15] = f2bf_hw(o_acc[dt][r] * lr[r]);
    }
}

// ---------------------------------------------------------------------------
extern "C" void kernel_launch(void* const* d_in, const int* in_sizes, int n_in,
                              void* d_out, int out_size, void* d_ws, size_t ws_size,
                              hipStream_t stream) {
    const float* x      = (const float*)d_in[0];
    const float* w_qkv  = (const float*)d_in[1];
    const float* w_proj = (const float*)d_in[2];
    float* out = (float*)d_out;

    unsigned short* Xb  = (unsigned short*)d_ws;          // 4M shorts
    unsigned short* Wqt = Xb  + (size_t)4 * 1024 * 1024;  // 3M
    unsigned short* Wpt = Wqt + (size_t)3 * 1024 * 1024;  // 1M
    unsigned short* Qb  = Wpt + (size_t)1 * 1024 * 1024;  // 4M
    unsigned short* Kb  = Qb  + (size_t)4 * 1024 * 1024;  // 4M
    unsigned short* Vb  = Kb  + (size_t)4 * 1024 * 1024;  // 4M (spacer)
    unsigned short* Vtb = Vb  + (size_t)4 * 1024 * 1024;  // 4M (written by gemm)
    unsigned short* Ob  = Vtb + (size_t)4 * 1024 * 1024;  // 4M  (56 MB total)

    // Split-K partials alias Qb..Vtb (32 MB, dead after flash).
    float* Pp = (float*)Qb;

    fused_convert_kernel<<<dim3(6144), 256, 0, stream>>>(
        x, Xb, w_qkv, Wqt, w_proj, Wpt);

    gemm_qkv_mfma<<<dim3(3 * D_MODEL / 128, BATCH * SEQ / 128), 256, 0, stream>>>(
        Xb, Wqt, Qb, Kb, Vtb);

    flash_attn_kernel<<<dim3(SEQ / 64 * BATCH * N_HEADS), 256, 0, stream>>>(
        Qb, Kb, Vtb, Ob);

    gemm_proj_splitk<<<dim3(D_MODEL / 128, BATCH * SEQ / 128, 2), 256, 0, stream>>>(
        Ob, Wpt, Pp);

    add_out_kernel<<<dim3(1024), 256, 0, stream>>>(Pp, out);
}

// Round 7
// 210.223 us; speedup vs baseline: 1.0935x; 1.0243x over previous
//
#include <hip/hip_runtime.h>
#include <cstdint>
#include <cstddef>

#define D_MODEL 1024
#define N_HEADS 16
#define HEAD_DIM 64
#define SEQ 2048
#define BATCH 2

typedef __attribute__((ext_vector_type(8))) short bf16x8;
typedef __attribute__((ext_vector_type(4))) float f32x4;

// Hardware bf16 convert (RNE): 1 VALU op per 2 elements.
__device__ __forceinline__ unsigned cvtpk_bf16(float lo, float hi) {
    unsigned r;
    asm("v_cvt_pk_bf16_f32 %0, %1, %2" : "=v"(r) : "v"(lo), "v"(hi));
    return r;
}
__device__ __forceinline__ unsigned short f2bf_hw(float f) {
    return (unsigned short)cvtpk_bf16(f, 0.f);
}

// async global->LDS, 16 B per lane; LDS dst must be wave-base + lane*16.
__device__ __forceinline__ void gload_lds16(const unsigned short* g, unsigned short* l) {
    __builtin_amdgcn_global_load_lds(
        (const __attribute__((address_space(1))) unsigned int*)g,
        (__attribute__((address_space(3))) unsigned int*)l, 16, 0, 0);
}

// s_waitcnt immediates (gfx9: vmcnt[3:0]|[15:14], expcnt[6:4], lgkmcnt[11:8])
#define WAITCNT_VM4 0x0F74   // vmcnt(4), expcnt/lgkmcnt = no-wait
#define WAITCNT_VM0 0x0F70   // vmcnt(0)

// ---------------------------------------------------------------------------
// Fused converts: x->bf16 | w_qkv->Wqt (permuted transpose, Q pre-scaled) |
// w_proj->Wpt.
// ---------------------------------------------------------------------------
__global__ __launch_bounds__(256) void fused_convert_kernel(
    const float* __restrict__ X, unsigned short* __restrict__ Xb,
    const float* __restrict__ Wq, unsigned short* __restrict__ Wqt,
    const float* __restrict__ Wp, unsigned short* __restrict__ Wpt)
{
    const int blk = blockIdx.x;
    const int tid = threadIdx.x;
    __shared__ float t[32][33];

    if (blk < 2048) {
        const int idx = blk * 256 + tid;
        const float4* src = (const float4*)X;
        float4 v0 = src[idx * 2], v1 = src[idx * 2 + 1];
        uint4 o;
        o.x = cvtpk_bf16(v0.x, v0.y);
        o.y = cvtpk_bf16(v0.z, v0.w);
        o.z = cvtpk_bf16(v1.x, v1.y);
        o.w = cvtpk_bf16(v1.z, v1.w);
        ((uint4*)Xb)[idx] = o;
    } else if (blk < 5120) {
        const int bb = blk - 2048;
        const int c0 = (bb % 96) * 32, r0 = (bb / 96) * 32;
        const int a = tid & 31, b = tid >> 5;
#pragma unroll
        for (int i = 0; i < 32; i += 8)
            t[b + i][a] = Wq[(size_t)(r0 + b + i) * (3 * D_MODEL) + c0 + a];
        __syncthreads();
#pragma unroll
        for (int i = 0; i < 32; i += 8) {
            const int c = c0 + b + i;
            const int which = c % 3;
            const int np = which * 1024 + c / 3;   // which*1024 + h*64 + d
            const float s = (which == 0) ? 0.125f : 1.0f;
            Wqt[(size_t)np * D_MODEL + r0 + a] = f2bf_hw(t[a][b + i] * s);
        }
    } else {
        const int bb = blk - 5120;
        const int c0 = (bb % 32) * 32, r0 = (bb / 32) * 32;
        const int a = tid & 31, b = tid >> 5;
#pragma unroll
        for (int i = 0; i < 32; i += 8)
            t[b + i][a] = Wp[(size_t)(r0 + b + i) * D_MODEL + c0 + a];
        __syncthreads();
#pragma unroll
        for (int i = 0; i < 32; i += 8)
            Wpt[(size_t)(c0 + b + i) * D_MODEL + r0 + a] = f2bf_hw(t[a][b + i]);
    }
}

// ---------------------------------------------------------------------------
// Pipelined GEMM core (R2/R4-proven): 128x128 tile, BK=32, triple-buffer LDS,
// stage depth 2, raw s_barrier + counted vmcnt(4) (never drains mid-loop).
// setprio around MFMA cluster (R4 vs R6 A/B: mildly positive in this
// 3-independent-barrier-groups/CU regime). LDS 48 KB -> 3 blocks/CU.
// ---------------------------------------------------------------------------
#define GEMM_PIPE3_BODY(A_, B_, KBASE, NITER, BX_, BY_)                        \
    const int tid = threadIdx.x;                                               \
    const int w = tid >> 6, lane = tid & 63;                                   \
    const int l15 = lane & 15, quad = lane >> 4;                               \
    const int wr = w >> 1, wc = w & 1;                                         \
    const int row0 = (BY_) * 128, col0 = (BX_) * 128;                          \
    __shared__ unsigned short As[3][4096];                                     \
    __shared__ unsigned short Bs[3][4096];                                     \
    const f32x4 zero4 = {0.f, 0.f, 0.f, 0.f};                                  \
    f32x4 acc[4][4];                                                           \
    _Pragma("unroll") for (int i = 0; i < 4; i++)                              \
        _Pragma("unroll") for (int j = 0; j < 4; j++) acc[i][j] = zero4;       \
    auto stage_ = [&](int sb_, int kt_) {                                      \
        const int k0 = (KBASE) + kt_ * 32 + quad * 8;                          \
        _Pragma("unroll") for (int i = 0; i < 2; i++) {                        \
            const int f = w * 2 + i;                                           \
            gload_lds16((A_) + (size_t)(row0 + f * 16 + l15) * D_MODEL + k0,   \
                        &As[sb_][f * 512 + lane * 8]);                         \
            gload_lds16((B_) + (size_t)(col0 + f * 16 + l15) * D_MODEL + k0,   \
                        &Bs[sb_][f * 512 + lane * 8]);                         \
        }                                                                      \
    };                                                                         \
    stage_(0, 0);                                                              \
    stage_(1, 1);                                                              \
    int sb = 0;                                                                \
    for (int kt = 0; kt < (NITER); kt++) {                                     \
        if (kt < (NITER) - 1) {                                                \
            __builtin_amdgcn_s_waitcnt(WAITCNT_VM4);                           \
            __builtin_amdgcn_s_barrier();                                      \
            if (kt + 2 < (NITER)) stage_((sb + 2 > 2) ? sb - 1 : sb + 2, kt + 2); \
        } else {                                                               \
            __builtin_amdgcn_s_waitcnt(WAITCNT_VM0);                           \
            __builtin_amdgcn_s_barrier();                                      \
        }                                                                      \
        bf16x8 af[4], bfr[4];                                                  \
        _Pragma("unroll") for (int i = 0; i < 4; i++)                          \
            af[i] = *(const bf16x8*)&As[sb][(wr * 4 + i) * 512 + lane * 8];    \
        _Pragma("unroll") for (int j = 0; j < 4; j++)                          \
            bfr[j] = *(const bf16x8*)&Bs[sb][(wc * 4 + j) * 512 + lane * 8];   \
        __builtin_amdgcn_s_setprio(1);                                         \
        _Pragma("unroll") for (int i = 0; i < 4; i++)                          \
            _Pragma("unroll") for (int j = 0; j < 4; j++)                      \
                acc[i][j] = __builtin_amdgcn_mfma_f32_16x16x32_bf16(           \
                    af[i], bfr[j], acc[i][j], 0, 0, 0);                        \
        __builtin_amdgcn_s_setprio(0);                                         \
        sb = (sb == 2) ? 0 : sb + 1;                                           \
    }

// GEMM1: Xb @ Wqt^T -> Q/K bf16 [bh][n][d]; V written directly transposed to
// Vt[bh][d][n] via an LDS-transposed epilogue: the R6 dword-scatter (4KB
// stride, 64 transactions/instr, +4us) becomes 256B-contiguous uint4 runs.
// T1 XCD swizzle: 96/XCD as 12(bx) x 8(by) rect -> ~5MB/XCD working set.
__global__ __launch_bounds__(256) void gemm_qkv_mfma(
    const unsigned short* __restrict__ A, const unsigned short* __restrict__ B,
    unsigned short* __restrict__ Q, unsigned short* __restrict__ Kq,
    unsigned short* __restrict__ Vt)
{
    const int lin = blockIdx.x + 24 * blockIdx.y;   // 0..767, %8 = XCD
    const int xcd = lin & 7, t = lin >> 3;          // t: 0..95
    const int bx = (xcd & 1) * 12 + t % 12;         // 0..23
    const int by = (xcd >> 1) * 8 + t / 12;         // 0..31
    GEMM_PIPE3_BODY(A, B, 0, 32, bx, by)
    const int nbase = col0 + wc * 64;              // wave-uniform, mult of 64
    const int which = col0 >> 10;                  // 0:Q 1:K 2:V (BLOCK-uniform)
    if (which < 2) {
        unsigned short* const dst = (which == 0) ? Q : Kq;
#pragma unroll
        for (int i = 0; i < 4; i++) {
            const int rowb = row0 + wr * 64 + i * 16 + quad * 4;
            const int bb = rowb >> 11, n = rowb & (SEQ - 1);
#pragma unroll
            for (int rp = 0; rp < 2; rp++) {
#pragma unroll
                for (int j = 0; j < 4; j++) {
                    const unsigned u = cvtpk_bf16(acc[i][j][2 * rp], acc[i][j][2 * rp + 1]);
                    const int idx = (nbase + j * 16 + l15) & 1023;  // h*64+d
                    const int h = idx >> 6, dd = idx & 63;
                    unsigned short* p =
                        dst + (((size_t)(bb * N_HEADS + h)) * SEQ + n + 2 * rp) * HEAD_DIM + dd;
                    p[0] = (unsigned short)u;
                    p[HEAD_DIM] = (unsigned short)(u >> 16);
                }
            }
        }
    } else {
        // V epilogue: LDS transpose in two 64-col halves (17KB of dead As).
        // LDS layout [c_loc][n] with 136-short padded stride (272B, 16B-mult):
        // writes 4-way bank conflict, reads 8-way -- ~450cyc total, vs ~16x
        // fewer global store transactions (uint4 runs of 256B along n).
        unsigned short* vt = &As[0][0];              // 64*136*2 = 17408B < 24KB
        const int n0 = row0 & (SEQ - 1);
        const int bb = row0 >> 11;
        const int vbase = col0 & 1023;               // mult of 128: h*64+d base
        __syncthreads();                             // K-loop LDS reads done
#pragma unroll
        for (int half = 0; half < 2; half++) {
            if (wc == half) {
#pragma unroll
                for (int i = 0; i < 4; i++) {
                    const int nl = wr * 64 + i * 16 + quad * 4;
#pragma unroll
                    for (int rp = 0; rp < 2; rp++) {
#pragma unroll
                        for (int j = 0; j < 4; j++) {
                            const unsigned u =
                                cvtpk_bf16(acc[i][j][2 * rp], acc[i][j][2 * rp + 1]);
                            const int c_loc = j * 16 + l15;          // 0..63
                            *(unsigned*)&vt[c_loc * 136 + nl + 2 * rp] = u;
                        }
                    }
                }
            }
            __syncthreads();
            // all 256 threads: 64 rows x 16 uint4 chunks, 4 per thread
#pragma unroll
            for (int pass = 0; pass < 4; pass++) {
                const int c_loc = pass * 16 + (tid >> 4);            // 0..63
                const int t16 = tid & 15;
                const uint4 v = *(const uint4*)&vt[c_loc * 136 + t16 * 8];
                const int vc = vbase + half * 64 + c_loc;            // h*64+d
                *(uint4*)&Vt[((size_t)(bb * N_HEADS + (vc >> 6)) * HEAD_DIM
                              + (vc & 63)) * SEQ + n0 + t16 * 8] = v;
            }
            if (half == 0) __syncthreads();          // before 2nd-half writes
        }
    }
}

// GEMM2: SPLIT-K=2, pipelined. Grid (8, 32, 2). K=512/block, NITER=16.
// T1 XCD swizzle per z-slice: 32/XCD as 4(bx) x 8(by) rectangle.
__global__ __launch_bounds__(256) void gemm_proj_splitk(
    const unsigned short* __restrict__ A, const unsigned short* __restrict__ B,
    float* __restrict__ P)
{
    const int lin = blockIdx.x + 8 * blockIdx.y;    // 0..255, %8 = XCD
    const int xcd = lin & 7, t = lin >> 3;          // t: 0..31
    const int bx = (xcd & 1) * 4 + t % 4;           // 0..7
    const int by = (xcd >> 1) * 8 + t / 4;          // 0..31
    const int kbase = blockIdx.z * 512;
    GEMM_PIPE3_BODY(A, B, kbase, 16, bx, by)
    float* const dst = P + (size_t)blockIdx.z * (4096ull * 1024ull);
#pragma unroll
    for (int i = 0; i < 4; i++) {
#pragma unroll
        for (int r = 0; r < 4; r++) {
            const int row = row0 + wr * 64 + i * 16 + quad * 4 + r;
#pragma unroll
            for (int j = 0; j < 4; j++) {
                const int c = col0 + wc * 64 + j * 16 + l15;
                dst[(size_t)row * D_MODEL + c] = acc[i][j][r];
            }
        }
    }
}

// out = P0 + P1 (fp32). 4M floats = 1M float4; 1024 blocks x 256 thr x 4.
__global__ __launch_bounds__(256) void add_out_kernel(
    const float* __restrict__ P, float* __restrict__ out)
{
    const float4* p0 = (const float4*)P;
    const float4* p1 = (const float4*)(P + 4096ull * 1024ull);
    float4* o = (float4*)out;
    const int base = (blockIdx.x * 256 + threadIdx.x) * 4;
#pragma unroll
    for (int j = 0; j < 4; j++) {
        float4 a = p0[base + j], b = p1[base + j];
        float4 r = {a.x + b.x, a.y + b.y, a.z + b.z, a.w + b.w};
        o[base + j] = r;
    }
}

// ---------------------------------------------------------------------------
// Flash attention v5 (unchanged): T13 defer-rescale, cvt_pk P-pack, per-lane
// l partial, setprio around MFMA (m191 regime: 4 independent blocks/CU).
// LDS 40 KB -> 4 blocks/CU, all 1024 blocks resident.
// ---------------------------------------------------------------------------
__global__ __launch_bounds__(256) void flash_attn_kernel(
    const unsigned short* __restrict__ Q,
    const unsigned short* __restrict__ K,
    const unsigned short* __restrict__ Vt,
    unsigned short* __restrict__ O)
{
    const int idx = blockIdx.x;
    const int bh = idx & 31;
    const int qt2 = idx >> 5;
    const int hi = qt2 >> 3, lo = qt2 & 7;
    const int qt = (hi == 0) ? lo : (hi == 1) ? 31 - lo : (hi == 2) ? lo + 8 : 23 - lo;

    const int tid = threadIdx.x;
    const int w = tid >> 6, lane = tid & 63;
    const int l15 = lane & 15, quad = lane >> 4;

    __shared__ unsigned short Ks[2][4096];
    __shared__ unsigned short Vs[2][4096];
    __shared__ unsigned short Ps[4][1024];

    bf16x8 qf[2];
    {
        const unsigned short* qrow =
            Q + ((size_t)bh * SEQ + qt * 64 + w * 16 + l15) * HEAD_DIM;
        qf[0] = *(const bf16x8*)(qrow + quad * 8);
        qf[1] = *(const bf16x8*)(qrow + 32 + quad * 8);
    }

    const f32x4 zero4 = {0.f, 0.f, 0.f, 0.f};
    f32x4 o_acc[4] = {zero4, zero4, zero4, zero4};
    float m_i = -1e30f, l_i = 0.f;

    auto stage = [&](int bf, int kt_t) {
        const int key0 = kt_t * 64;
#pragma unroll
        for (int i = 0; i < 2; i++) {
            const int f = w * 2 + i;
            const int ct = f >> 1, kh = f & 1;
            gload_lds16(K + ((size_t)bh * SEQ + key0 + ct * 16 + l15) * HEAD_DIM
                          + kh * 32 + quad * 8,
                        &Ks[bf][f * 512 + lane * 8]);
            gload_lds16(Vt + ((size_t)bh * HEAD_DIM + ct * 16 + l15) * SEQ
                           + key0 + kh * 32 + quad * 8,
                        &Vs[bf][f * 512 + lane * 8]);
        }
    };

    stage(0, 0);
    int buf = 0;

    const int qg = qt * 64 + w * 16 + l15;

    for (int kt = 0; kt <= qt; kt++) {
        __syncthreads();
        if (kt < qt) stage(buf ^ 1, kt + 1);

        f32x4 st[4] = {zero4, zero4, zero4, zero4};
        __builtin_amdgcn_s_setprio(1);
#pragma unroll
        for (int kh = 0; kh < 2; kh++) {
#pragma unroll
            for (int ct = 0; ct < 4; ct++) {
                bf16x8 kf = *(const bf16x8*)&Ks[buf][(ct * 2 + kh) * 512 + lane * 8];
                st[ct] = __builtin_amdgcn_mfma_f32_16x16x32_bf16(kf, qf[kh], st[ct], 0, 0, 0);
            }
        }
        __builtin_amdgcn_s_setprio(0);

        float mt = -1e30f;
        if (kt == qt) {
#pragma unroll
            for (int ct = 0; ct < 4; ct++) {
#pragma unroll
                for (int r = 0; r < 4; r++) {
                    const int kg = kt * 64 + ct * 16 + quad * 4 + r;
                    float v = (kg > qg) ? -1e30f : st[ct][r];
                    st[ct][r] = v;
                    mt = fmaxf(mt, v);
                }
            }
        } else {
#pragma unroll
            for (int ct = 0; ct < 4; ct++)
#pragma unroll
                for (int r = 0; r < 4; r++)
                    mt = fmaxf(mt, st[ct][r]);
        }
        mt = fmaxf(mt, __shfl_xor(mt, 16));
        mt = fmaxf(mt, __shfl_xor(mt, 32));

        float mn = m_i;
        if (!__all(mt <= m_i + 8.0f)) {
            mn = fmaxf(m_i, mt);
            const float alpha = __expf(m_i - mn);
            m_i = mn;
            l_i *= alpha;
            float ar[4];
#pragma unroll
            for (int r = 0; r < 4; r++)
                ar[r] = __shfl(alpha, (lane & 48) | (quad * 4 + r));
#pragma unroll
            for (int dt = 0; dt < 4; dt++)
#pragma unroll
                for (int r = 0; r < 4; r++)
                    o_acc[dt][r] *= ar[r];
        }

        float ls = 0.f;
#pragma unroll
        for (int ct = 0; ct < 4; ct++) {
            const float p0 = __expf(st[ct][0] - mn);
            const float p1 = __expf(st[ct][1] - mn);
            const float p2 = __expf(st[ct][2] - mn);
            const float p3 = __expf(st[ct][3] - mn);
            ls += (p0 + p1) + (p2 + p3);
            uint2 pk2;
            pk2.x = cvtpk_bf16(p0, p1);
            pk2.y = cvtpk_bf16(p2, p3);
            const int addr = (ct >> 1) * 512 + ((ct & 1) * 2 + (quad >> 1)) * 128
                           + l15 * 8 + (quad & 1) * 4;
            *(uint2*)&Ps[w][addr] = pk2;
        }
        l_i += ls;

        __builtin_amdgcn_s_setprio(1);
#pragma unroll
        for (int kh = 0; kh < 2; kh++) {
            bf16x8 pa = *(const bf16x8*)&Ps[w][kh * 512 + quad * 128 + l15 * 8];
#pragma unroll
            for (int dt = 0; dt < 4; dt++) {
                bf16x8 vf = *(const bf16x8*)&Vs[buf][(dt * 2 + kh) * 512 + lane * 8];
                o_acc[dt] = __builtin_amdgcn_mfma_f32_16x16x32_bf16(pa, vf, o_acc[dt], 0, 0, 0);
            }
        }
        __builtin_amdgcn_s_setprio(0);
        buf ^= 1;
    }

    l_i += __shfl_xor(l_i, 16);
    l_i += __shfl_xor(l_i, 32);
    const float linv = 1.0f / l_i;
    float lr[4];
#pragma unroll
    for (int r = 0; r < 4; r++)
        lr[r] = __shfl(linv, (lane & 48) | (quad * 4 + r));

    const int b = bh >> 4, h = bh & 15;
#pragma unroll
    for (int r = 0; r < 4; r++) {
        const int q = qt * 64 + w * 16 + quad * 4 + r;
        unsigned short* orow = O + ((size_t)b * SEQ + q) * D_MODEL + h * HEAD_DIM;
#pragma unroll
        for (int dt = 0; dt < 4; dt++)
            orow[dt * 16 + l15] = f2bf_hw(o_acc[dt][r] * lr[r]);
    }
}

// ---------------------------------------------------------------------------
extern "C" void kernel_launch(void* const* d_in, const int* in_sizes, int n_in,
                              void* d_out, int out_size, void* d_ws, size_t ws_size,
                              hipStream_t stream) {
    const float* x      = (const float*)d_in[0];
    const float* w_qkv  = (const float*)d_in[1];
    const float* w_proj = (const float*)d_in[2];
    float* out = (float*)d_out;

    unsigned short* Xb  = (unsigned short*)d_ws;          // 4M shorts
    unsigned short* Wqt = Xb  + (size_t)4 * 1024 * 1024;  // 3M
    unsigned short* Wpt = Wqt + (size_t)3 * 1024 * 1024;  // 1M
    unsigned short* Qb  = Wpt + (size_t)1 * 1024 * 1024;  // 4M
    unsigned short* Kb  = Qb  + (size_t)4 * 1024 * 1024;  // 4M
    unsigned short* Vb  = Kb  + (size_t)4 * 1024 * 1024;  // 4M (spacer)
    unsigned short* Vtb = Vb  + (size_t)4 * 1024 * 1024;  // 4M (written by gemm)
    unsigned short* Ob  = Vtb + (size_t)4 * 1024 * 1024;  // 4M  (56 MB total)

    // Split-K partials alias Qb..Vtb (32 MB, dead after flash).
    float* Pp = (float*)Qb;

    fused_convert_kernel<<<dim3(6144), 256, 0, stream>>>(
        x, Xb, w_qkv, Wqt, w_proj, Wpt);

    gemm_qkv_mfma<<<dim3(3 * D_MODEL / 128, BATCH * SEQ / 128), 256, 0, stream>>>(
        Xb, Wqt, Qb, Kb, Vtb);

    flash_attn_kernel<<<dim3(SEQ / 64 * BATCH * N_HEADS), 256, 0, stream>>>(
        Qb, Kb, Vtb, Ob);

    gemm_proj_splitk<<<dim3(D_MODEL / 128, BATCH * SEQ / 128, 2), 256, 0, stream>>>(
        Ob, Wpt, Pp);

    add_out_kernel<<<dim3(1024), 256, 0, stream>>>(Pp, out);
}